// Round 9
// baseline (23.998 us; speedup 1.0000x reference)
//
#include <hip/hip_runtime.h>

// MipNeRF split into 2 kernels:
//  phase 1 (wave/ray): blur + scan + inverse-CDF -> writes t_coarse, t_fine.
//  phase 2 (linear emit): one thread per 4-float span of means/covs; store
//  addresses are EXACTLY linear in thread index per region (fill-kernel
//  shaped). Fine t's are read back from out's own t_fine region.

constexpr int B_RAYS = 8192;
constexpr int S      = 128;
constexpr int SP1    = 129;
constexpr float F32_EPS = 1.1920928955078125e-07f;
constexpr float USTEP   = (1.0f - F32_EPS) / 128.0f;
constexpr float R_SCALE = 128.0f / (1.0f - F32_EPS);

// flat output offsets (t_coarse, means_c, covs_c, t_fine, means_f, covs_f)
constexpr long long O_TC = 0;
constexpr long long O_MC = O_TC + (long long)B_RAYS * SP1;
constexpr long long O_CC = O_MC + (long long)B_RAYS * S * 3;
constexpr long long O_TF = O_CC + (long long)B_RAYS * S * 3;
constexpr long long O_MF = O_TF + (long long)B_RAYS * SP1;
constexpr long long O_CF = O_MF + (long long)B_RAYS * S * 3;

constexpr int SPANS      = 96;                    // float4 spans per ray per region
constexpr int UNITS_CAST = B_RAYS * SPANS;        // 786432 (= 12288 waves, aligned)

typedef float vf4 __attribute__((ext_vector_type(4)));

__device__ __forceinline__ float frcp(float x) { return __builtin_amdgcn_rcpf(x); }

template<int CTRL, int RM>
__device__ __forceinline__ float dpp_addf(float x) {
    int m = __builtin_amdgcn_update_dpp(0, __builtin_bit_cast(int, x),
                                        CTRL, RM, 0xF, true);
    return x + __builtin_bit_cast(float, m);
}
template<int CTRL>
__device__ __forceinline__ float dpp_movf(float x) {
    int m = __builtin_amdgcn_update_dpp(0, __builtin_bit_cast(int, x),
                                        CTRL, 0xF, 0xF, true);
    return __builtin_bit_cast(float, m);
}

__device__ __forceinline__ void st_nt(float* p, float v) {
    __builtin_nontemporal_store(v, p);
}
__device__ __forceinline__ void st_nt4(float* p, float4 v) {
    __builtin_nontemporal_store(__builtin_bit_cast(vf4, v),
                                reinterpret_cast<vf4*>(p));
}

// conical_frustum_to_gaussian, stable branch (rcp instead of exact div)
__device__ __forceinline__ void frustum(float t0, float t1, float rad2,
                                        float& tm, float& tv, float& rv)
{
    float mu  = 0.5f * (t0 + t1);
    float hw  = 0.5f * (t1 - t0);
    float mu2 = mu * mu, hw2 = hw * hw, hw4 = hw2 * hw2;
    float den  = fmaf(3.0f, mu2, hw2);
    float rden = frcp(den);
    tm = fmaf(2.0f * mu * hw2, rden, mu);
    tv = hw2 * (1.0f / 3.0f)
       - (4.0f / 15.0f) * (hw4 * fmaf(12.0f, mu2, -hw2)) * (rden * rden);
    rv = rad2 * (0.25f * mu2 + (5.0f / 12.0f) * hw2 - (4.0f / 15.0f) * hw4 * rden);
}

__device__ __forceinline__ float sel3(int c, float x, float y, float z)
{
    return (c == 0) ? x : ((c == 1) ? y : z);
}

// smallest s in [0,129] with (float)s * USTEP >= c  (exact predicate)
__device__ __forceinline__ int smin_of(float c)
{
    int s = (int)ceilf(c * R_SCALE);
    s = s < 0 ? 0 : (s > 129 ? 129 : s);
    #pragma unroll
    for (int it = 0; it < 2; ++it)
        if (s > 0 && (float)(s - 1) * USTEP >= c) --s;
    #pragma unroll
    for (int it = 0; it < 2; ++it)
        if (s < 129 && (float)s * USTEP < c) ++s;
    return s;
}

// ---------------- phase 1: t_coarse + t_fine ----------------
__global__ __launch_bounds__(256) void sample_kernel(
    const float* __restrict__ nearp,
    const float* __restrict__ farp,
    const float* __restrict__ weights,
    float* __restrict__ out)
{
    const int tid = threadIdx.x;
    const int w   = tid >> 6;
    const int l   = tid & 63;
    const int b   = (blockIdx.x << 2) + w;

    __shared__ float4 s_pay[4][132];   // per-sample {c0, dc, b0, b1}

    const float2 wv = *reinterpret_cast<const float2*>(weights + (long long)b * S + 2*l);
    const float nv = nearp[b], fv = farp[b];

    auto bin = [&](int k) {
        float t = (float)k * (1.0f / 128.0f);
        return nv * (1.0f - t) + fv * t;     // bit-identical to reference
    };

    // ---- t_coarse out ----
    {
        float* ot = out + O_TC + (long long)b * SP1;
        st_nt(ot + l,      bin(l));
        st_nt(ot + l + 64, bin(l + 64));
        if (l == 0) st_nt(ot + 128, bin(128));
    }

    // ---- blur weights; DPP +-1 shifts ----
    float wprev = dpp_movf<0x138>(wv.y);  if (l == 0)  wprev = wv.x;  // wave_shr:1
    float wnext = dpp_movf<0x130>(wv.x);  if (l == 63) wnext = wv.y;  // wave_shl:1
    float m0 = fmaxf(wprev, wv.x), m1 = fmaxf(wv.x, wv.y), m2 = fmaxf(wv.y, wnext);
    float wb0 = 0.5f * (m0 + m1) + 0.01f;
    float wb1 = 0.5f * (m1 + m2) + 0.01f;

    // ---- wave64 inclusive scan of pair sums via DPP ----
    float ps = wb0 + wb1;
    float x  = ps;
    x = dpp_addf<0x111, 0xF>(x);   // row_shr:1
    x = dpp_addf<0x112, 0xF>(x);   // row_shr:2
    x = dpp_addf<0x114, 0xF>(x);   // row_shr:4
    x = dpp_addf<0x118, 0xF>(x);   // row_shr:8
    x = dpp_addf<0x142, 0xA>(x);   // row_bcast15 -> rows 1,3
    x = dpp_addf<0x143, 0xC>(x);   // row_bcast31 -> rows 2,3
    float incl  = x;
    float total = __builtin_bit_cast(float,
        __builtin_amdgcn_readlane(__builtin_bit_cast(int, incl), 63));

    float pad   = fmaxf(1e-5f - total, 0.0f);
    float wstot = total + pad;
    float inv   = frcp(wstot);
    float padk  = pad * (1.0f / 128.0f);
    float excl  = incl - ps;

    // cdf entries this lane owns: A=cdf[2l], B=cdf[2l+1], C=cdf[2l+2]
    float Av = (l == 0)  ? 0.0f
             : fminf((excl + (float)(2*l) * padk) * inv, 1.0f);
    float Bv = fminf((excl + wb0 + (float)(2*l + 1) * padk) * inv, 1.0f);
    float Cv = (l == 63) ? 1.0f
             : fminf((incl + (float)(2*l + 2) * padk) * inv, 1.0f);

    // ---- run-scatter ----
    int sm0 = smin_of(Av);
    int sm1 = smin_of(Bv);
    int sm2 = smin_of(Cv);
    {
        float4 payA = make_float4(Av, Bv - Av, bin(2*l),     bin(2*l + 1));
        float4 payB = make_float4(Bv, Cv - Bv, bin(2*l + 1), bin(2*l + 2));
        for (int s2 = sm0; s2 < sm1; ++s2) s_pay[w][s2] = payA;
        for (int s2 = sm1; s2 < sm2; ++s2) s_pay[w][s2] = payB;
    }
    __builtin_amdgcn_wave_barrier();

    // ---- t_fine out ----
    auto tf_of = [&](int s) -> float {
        float4 p = s_pay[w][s];
        float u  = (float)s * USTEP;
        float tt = (u - p.x) * frcp(p.y);
        if (!(tt == tt)) tt = 0.0f;              // nan_to_num
        tt = fminf(fmaxf(tt, 0.0f), 1.0f);       // clip (inf -> 1)
        return p.z + tt * (p.w - p.z);
    };
    {
        float* ot = out + O_TF + (long long)b * SP1;
        st_nt(ot + l,      tf_of(l));
        st_nt(ot + l + 64, tf_of(l + 64));
        if (l == 0) st_nt(ot + 128, tf_of(128));
    }
}

// ---------------- phase 2: linear means/covs emit ----------------
__global__ __launch_bounds__(256) void emit_kernel(
    const float* __restrict__ origins,
    const float* __restrict__ directions,
    const float* __restrict__ radii,
    const float* __restrict__ nearp,
    const float* __restrict__ farp,
    float* out)
{
    const int idx  = blockIdx.x * 256 + threadIdx.x;      // 0 .. 2*UNITS_CAST-1
    const bool fine = idx >= UNITS_CAST;                   // wave-uniform
    const int r    = fine ? idx - UNITS_CAST : idx;
    const int ray  = (int)(((unsigned long long)(unsigned)r * 2863311531ull) >> 38); // r/96
    const int m    = r - ray * SPANS;
    const int k0   = m + ((m * 43691) >> 17);              // m + m/3 = floor(4m/3)
    const int rr   = 4*m - 3*k0;

    // t-values for intervals k0, k0+1
    float t0, t1, t2;
    if (fine) {
        const float* tf = out + O_TF + (long long)ray * SP1;
        t0 = tf[k0]; t1 = tf[k0 + 1]; t2 = tf[k0 + 2];
    } else {
        float nv = nearp[ray], fv = farp[ray];
        float u0 = (float)k0 * (1.0f / 128.0f);
        float u1 = (float)(k0 + 1) * (1.0f / 128.0f);
        float u2 = (float)(k0 + 2) * (1.0f / 128.0f);
        t0 = nv * (1.0f - u0) + fv * u0;
        t1 = nv * (1.0f - u1) + fv * u1;
        t2 = nv * (1.0f - u2) + fv * u2;
    }

    // ray geometry (lanes mostly share a ray -> cached)
    const float ox = origins[3*ray+0], oy = origins[3*ray+1], oz = origins[3*ray+2];
    const float dx = directions[3*ray+0], dy = directions[3*ray+1], dz = directions[3*ray+2];
    const float rad  = radii[ray];
    const float rad2 = rad * rad;
    const float axx = dx*dx, ayy = dy*dy, azz = dz*dz;
    const float dmag2  = fmaxf(axx + ayy + azz, 1e-10f);
    const float rdmag2 = frcp(dmag2);
    const float nxx = 1.0f - axx * rdmag2;
    const float nyy = 1.0f - ayy * rdmag2;
    const float nzz = 1.0f - azz * rdmag2;

    float tmA, tvA, rvA, tmB, tvB, rvB;
    frustum(t0, t1, rad2, tmA, tvA, rvA);
    frustum(t1, t2, rad2, tmB, tvB, rvB);

    float4 mv, cv;
    #pragma unroll
    for (int e = 0; e < 4; ++e) {
        int  rc   = rr + e;
        bool useB = rc >= 3;
        int  c    = useB ? rc - 3 : rc;
        float tm = useB ? tmB : tmA;
        float tv = useB ? tvB : tvA;
        float rv = useB ? rvB : rvA;
        (&mv.x)[e] = sel3(c, dx, dy, dz) * tm + sel3(c, ox, oy, oz);
        (&cv.x)[e] = tv * sel3(c, axx, ayy, azz) + rv * sel3(c, nxx, nyy, nzz);
    }
    // store address = region_base + 16B * r  -> exactly linear per region
    const long long fo = 4LL * r;
    st_nt4(out + (fine ? O_MF : O_MC) + fo, mv);
    st_nt4(out + (fine ? O_CF : O_CC) + fo, cv);
}

extern "C" void kernel_launch(void* const* d_in, const int* in_sizes, int n_in,
                              void* d_out, int out_size, void* d_ws, size_t ws_size,
                              hipStream_t stream)
{
    const float* origins    = (const float*)d_in[0];
    const float* directions = (const float*)d_in[1];
    const float* radii      = (const float*)d_in[2];
    const float* nearp      = (const float*)d_in[3];
    const float* farp       = (const float*)d_in[4];
    const float* weights    = (const float*)d_in[5];
    float* out = (float*)d_out;

    sample_kernel<<<B_RAYS / 4, 256, 0, stream>>>(nearp, farp, weights, out);
    emit_kernel<<<(2 * UNITS_CAST) / 256, 256, 0, stream>>>(
        origins, directions, radii, nearp, farp, out);
}

// Round 10
// 17.650 us; speedup vs baseline: 1.3597x; 1.3597x over previous
//
#include <hip/hip_runtime.h>

// MipNeRF coarse cast + blur/inverse-CDF resample + fine cast.
// One 64-lane wave per ray; 256-thread blocks = 4 independent waves.
// R7 structure (DPP scan, run-scatter sampling, rcp divides, float4 stores).
// Store policy: NT for EARLY bursts (t_coarse, coarse means/covs — drain in
// background), REGULAR for the FINAL bursts (t_fine, fine means/covs — land
// in L2/L3 so the end-of-kernel fence doesn't wait on HBM).

constexpr int B_RAYS = 8192;
constexpr int S      = 128;
constexpr int SP1    = 129;
constexpr float F32_EPS = 1.1920928955078125e-07f;
constexpr float USTEP   = (1.0f - F32_EPS) / 128.0f;
constexpr float R_SCALE = 128.0f / (1.0f - F32_EPS);

// flat output offsets (t_coarse, means_c, covs_c, t_fine, means_f, covs_f)
constexpr long long O_TC = 0;
constexpr long long O_MC = O_TC + (long long)B_RAYS * SP1;
constexpr long long O_CC = O_MC + (long long)B_RAYS * S * 3;
constexpr long long O_TF = O_CC + (long long)B_RAYS * S * 3;
constexpr long long O_MF = O_TF + (long long)B_RAYS * SP1;
constexpr long long O_CF = O_MF + (long long)B_RAYS * S * 3;

typedef float vf4 __attribute__((ext_vector_type(4)));

__device__ __forceinline__ float frcp(float x) { return __builtin_amdgcn_rcpf(x); }

template<int CTRL, int RM>
__device__ __forceinline__ float dpp_addf(float x) {
    int m = __builtin_amdgcn_update_dpp(0, __builtin_bit_cast(int, x),
                                        CTRL, RM, 0xF, true);
    return x + __builtin_bit_cast(float, m);
}
template<int CTRL>
__device__ __forceinline__ float dpp_movf(float x) {
    int m = __builtin_amdgcn_update_dpp(0, __builtin_bit_cast(int, x),
                                        CTRL, 0xF, 0xF, true);
    return __builtin_bit_cast(float, m);
}

__device__ __forceinline__ void st_nt(float* p, float v) {
    __builtin_nontemporal_store(v, p);
}
__device__ __forceinline__ void st_nt4(float* p, float4 v) {
    __builtin_nontemporal_store(__builtin_bit_cast(vf4, v),
                                reinterpret_cast<vf4*>(p));
}
__device__ __forceinline__ void st4(float* p, float4 v) {
    *reinterpret_cast<float4*>(p) = v;
}

// conical_frustum_to_gaussian, stable branch (rcp instead of exact div)
__device__ __forceinline__ void frustum(float t0, float t1, float rad2,
                                        float& tm, float& tv, float& rv)
{
    float mu  = 0.5f * (t0 + t1);
    float hw  = 0.5f * (t1 - t0);
    float mu2 = mu * mu, hw2 = hw * hw, hw4 = hw2 * hw2;
    float den  = fmaf(3.0f, mu2, hw2);
    float rden = frcp(den);
    tm = fmaf(2.0f * mu * hw2, rden, mu);
    tv = hw2 * (1.0f / 3.0f)
       - (4.0f / 15.0f) * (hw4 * fmaf(12.0f, mu2, -hw2)) * (rden * rden);
    rv = rad2 * (0.25f * mu2 + (5.0f / 12.0f) * hw2 - (4.0f / 15.0f) * hw4 * rden);
}

__device__ __forceinline__ float sel3(int c, float x, float y, float z)
{
    return (c == 0) ? x : ((c == 1) ? y : z);
}

// smallest s in [0,129] with (float)s * USTEP >= c  (exact predicate)
__device__ __forceinline__ int smin_of(float c)
{
    int s = (int)ceilf(c * R_SCALE);
    s = s < 0 ? 0 : (s > 129 ? 129 : s);
    #pragma unroll
    for (int it = 0; it < 2; ++it)
        if (s > 0 && (float)(s - 1) * USTEP >= c) --s;
    #pragma unroll
    for (int it = 0; it < 2; ++it)
        if (s < 129 && (float)s * USTEP < c) ++s;
    return s;
}

__global__ __launch_bounds__(256) void mipnerf_kernel(
    const float* __restrict__ origins,
    const float* __restrict__ directions,
    const float* __restrict__ radii,
    const float* __restrict__ nearp,
    const float* __restrict__ farp,
    const float* __restrict__ weights,
    float* __restrict__ out)
{
    const int tid = threadIdx.x;
    const int w   = tid >> 6;
    const int l   = tid & 63;
    const int b   = (blockIdx.x << 2) + w;

    __shared__ float4 s_pay[4][132];   // per-sample {c0, dc, b0, b1}
    __shared__ float4 s_fr[4][128];    // per-interval {t_mean, t_var, r_var, -}

    const float2 wv = *reinterpret_cast<const float2*>(weights + (long long)b * S + 2*l);
    const float ox = origins[3*b+0], oy = origins[3*b+1], oz = origins[3*b+2];
    const float dx = directions[3*b+0], dy = directions[3*b+1], dz = directions[3*b+2];
    const float rad = radii[b];
    const float nv = nearp[b], fv = farp[b];

    const float rad2   = rad * rad;
    const float axx = dx*dx, ayy = dy*dy, azz = dz*dz;
    const float dmag2  = fmaxf(axx + ayy + azz, 1e-10f);
    const float rdmag2 = frcp(dmag2);
    const float nxx = 1.0f - axx * rdmag2;
    const float nyy = 1.0f - ayy * rdmag2;
    const float nzz = 1.0f - azz * rdmag2;

    auto bin = [&](int k) {
        float t = (float)k * (1.0f / 128.0f);
        return nv * (1.0f - t) + fv * t;     // bit-identical to reference
    };

    // ---- t_coarse out (NT: early burst) ----
    {
        float* ot = out + O_TC + (long long)b * SP1;
        st_nt(ot + l,      bin(l));
        st_nt(ot + l + 64, bin(l + 64));
        if (l == 0) st_nt(ot + 128, bin(128));
    }

    // ---- coarse frustum (2 intervals/lane) -> LDS float4 ----
    #pragma unroll
    for (int j = 0; j < 2; ++j) {
        int i = l + 64*j;
        float tm, tv, rv;
        frustum(bin(i), bin(i + 1), rad2, tm, tv, rv);
        s_fr[w][i] = make_float4(tm, tv, rv, 0.0f);
    }
    __builtin_amdgcn_wave_barrier();

    // emit float4 means + float4 covs for span m (floats [4m,4m+4))
    auto emit_span = [&](int m, float* __restrict__ om, float* __restrict__ oc,
                         bool nt) {
        int k0 = m + m / 3;            // floor(4m/3)
        int r  = 4*m - 3*k0;
        float4 fA = s_fr[w][k0], fB = s_fr[w][k0 + 1];
        float4 mv, cv;
        #pragma unroll
        for (int e = 0; e < 4; ++e) {
            int  rc   = r + e;
            bool useB = rc >= 3;
            int  c    = useB ? rc - 3 : rc;
            float tm = useB ? fB.x : fA.x;
            float tv = useB ? fB.y : fA.y;
            float rv = useB ? fB.z : fA.z;
            (&mv.x)[e] = sel3(c, dx, dy, dz) * tm + sel3(c, ox, oy, oz);
            (&cv.x)[e] = tv * sel3(c, axx, ayy, azz) + rv * sel3(c, nxx, nyy, nzz);
        }
        if (nt) { st_nt4(om + 4*m, mv); st_nt4(oc + 4*m, cv); }
        else    { st4(om + 4*m, mv);    st4(oc + 4*m, cv); }
    };

    // ---- coarse emit (NT: early burst, drains during resample) ----
    {
        float* om = out + O_MC + (long long)b * 384;
        float* oc = out + O_CC + (long long)b * 384;
        emit_span(l, om, oc, true);
        if (l < 32) emit_span(l + 64, om, oc, true);
    }

    // ---- blur weights (lane holds w[2l], w[2l+1]); DPP +-1 shifts ----
    float wprev = dpp_movf<0x138>(wv.y);  if (l == 0)  wprev = wv.x;  // wave_shr:1
    float wnext = dpp_movf<0x130>(wv.x);  if (l == 63) wnext = wv.y;  // wave_shl:1
    float m0 = fmaxf(wprev, wv.x), m1 = fmaxf(wv.x, wv.y), m2 = fmaxf(wv.y, wnext);
    float wb0 = 0.5f * (m0 + m1) + 0.01f;
    float wb1 = 0.5f * (m1 + m2) + 0.01f;

    // ---- wave64 inclusive scan of pair sums via DPP ----
    float ps = wb0 + wb1;
    float x  = ps;
    x = dpp_addf<0x111, 0xF>(x);   // row_shr:1
    x = dpp_addf<0x112, 0xF>(x);   // row_shr:2
    x = dpp_addf<0x114, 0xF>(x);   // row_shr:4
    x = dpp_addf<0x118, 0xF>(x);   // row_shr:8
    x = dpp_addf<0x142, 0xA>(x);   // row_bcast15 -> rows 1,3
    x = dpp_addf<0x143, 0xC>(x);   // row_bcast31 -> rows 2,3
    float incl  = x;
    float total = __builtin_bit_cast(float,
        __builtin_amdgcn_readlane(__builtin_bit_cast(int, incl), 63));

    float pad   = fmaxf(1e-5f - total, 0.0f);
    float wstot = total + pad;
    float inv   = frcp(wstot);
    float padk  = pad * (1.0f / 128.0f);
    float excl  = incl - ps;

    // cdf entries this lane owns: B=cdf[2l+1], C=cdf[2l+2]; A=cdf[2l] via DPP
    float Bv = fminf((excl + wb0 + (float)(2*l + 1) * padk) * inv, 1.0f);
    float Cv = (l == 63) ? 1.0f
             : fminf((incl + (float)(2*l + 2) * padk) * inv, 1.0f);
    float Av = dpp_movf<0x138>(Cv);          // wave_shr:1; lane0 -> 0.0 = cdf[0]

    // ---- run-scatter: interval k owns samples [smin(cdf[k]), smin(cdf[k+1])) ----
    int sm0 = smin_of(Av);
    int sm1 = smin_of(Bv);
    int sm2 = smin_of(Cv);                   // l==63: smin(1.0)=129 sentinel
    {
        float4 payA = make_float4(Av, Bv - Av, bin(2*l),     bin(2*l + 1));
        float4 payB = make_float4(Bv, Cv - Bv, bin(2*l + 1), bin(2*l + 2));
        for (int s2 = sm0; s2 < sm1; ++s2) s_pay[w][s2] = payA;
        for (int s2 = sm1; s2 < sm2; ++s2) s_pay[w][s2] = payB;
    }
    __builtin_amdgcn_wave_barrier();

    // ---- sample: ONE b128 read per sample ----
    auto sample_one = [&](int s) -> float {
        float4 p = s_pay[w][s];
        float u  = (float)s * USTEP;
        float tt = (u - p.x) * frcp(p.y);
        if (!(tt == tt)) tt = 0.0f;              // nan_to_num
        tt = fminf(fmaxf(tt, 0.0f), 1.0f);       // clip (inf -> 1)
        return p.z + tt * (p.w - p.z);
    };
    float tf0 = sample_one(l);
    float tf1 = sample_one(l + 64);
    float tf2 = sample_one(128);
    {
        float* ot = out + O_TF + (long long)b * SP1;     // regular: final phase
        ot[l]      = tf0;
        ot[l + 64] = tf1;
        if (l == 0) ot[128] = tf2;
    }

    // ---- fine frustum: neighbors via DPP ----
    float tf1_0 = __builtin_bit_cast(float,
        __builtin_amdgcn_readfirstlane(__builtin_bit_cast(int, tf1))); // t_fine[64]
    float tA1 = dpp_movf<0x130>(tf0);  if (l == 63) tA1 = tf1_0;   // t_fine[l+1]
    float tB1 = dpp_movf<0x130>(tf1);  if (l == 63) tB1 = tf2;     // t_fine[l+65]
    {
        float tm, tv, rv;
        frustum(tf0, tA1, rad2, tm, tv, rv);
        s_fr[w][l] = make_float4(tm, tv, rv, 0.0f);
        frustum(tf1, tB1, rad2, tm, tv, rv);
        s_fr[w][l + 64] = make_float4(tm, tv, rv, 0.0f);
    }
    __builtin_amdgcn_wave_barrier();

    // ---- fine emit (REGULAR stores: tail lands in L2/L3, fast EOP drain) ----
    {
        float* om = out + O_MF + (long long)b * 384;
        float* oc = out + O_CF + (long long)b * 384;
        emit_span(l, om, oc, false);
        if (l < 32) emit_span(l + 64, om, oc, false);
    }
}

extern "C" void kernel_launch(void* const* d_in, const int* in_sizes, int n_in,
                              void* d_out, int out_size, void* d_ws, size_t ws_size,
                              hipStream_t stream)
{
    const float* origins    = (const float*)d_in[0];
    const float* directions = (const float*)d_in[1];
    const float* radii      = (const float*)d_in[2];
    const float* nearp      = (const float*)d_in[3];
    const float* farp       = (const float*)d_in[4];
    const float* weights    = (const float*)d_in[5];
    float* out = (float*)d_out;

    mipnerf_kernel<<<B_RAYS / 4, 256, 0, stream>>>(
        origins, directions, radii, nearp, farp, weights, out);
}